// Round 1
// baseline (730.321 us; speedup 1.0000x reference)
//
#include <hip/hip_runtime.h>
#include <hip/hip_bf16.h>

// Problem constants (from reference)
#define BB 512
#define NN 1024
#define MM 128
#define OUTD 256
#define MOLD 256
#define IND 512
#define K1 512          // OUTD + MOLD
#define RROWS 65536     // BB * MM

typedef float f32x4 __attribute__((ext_vector_type(4)));
typedef short s16x8 __attribute__((ext_vector_type(8)));
typedef __bf16 bf16x8 __attribute__((ext_vector_type(8)));

#define AS_GLOBAL const __attribute__((address_space(1))) void
#define AS_LDS __attribute__((address_space(3))) void

__device__ __forceinline__ unsigned short f2bf(float f) {
    unsigned int u = __builtin_bit_cast(unsigned int, f);
    u = (u + 0x7fffu + ((u >> 16) & 1u)) >> 16;
    return (unsigned short)u;
}

// ---------------- prep: W1, W2 fp32 -> bf16 ----------------
// grid: 256 blocks x 256 threads, 4 elems each per matrix (512*512 = 262144 elems)
__global__ __launch_bounds__(256) void prep_weights(
    const float* __restrict__ W1, const float* __restrict__ W2,
    unsigned short* __restrict__ W1b, unsigned short* __restrict__ W2b) {
    int i = blockIdx.x * 256 + threadIdx.x;  // float4 index, < 65536
    float4 a = ((const float4*)W1)[i];
    ushort4 pa;
    pa.x = f2bf(a.x); pa.y = f2bf(a.y); pa.z = f2bf(a.z); pa.w = f2bf(a.w);
    ((ushort4*)W1b)[i] = pa;
    float4 b = ((const float4*)W2)[i];
    ushort4 pb;
    pb.x = f2bf(b.x); pb.y = f2bf(b.y); pb.z = f2bf(b.z); pb.w = f2bf(b.w);
    ((ushort4*)W2b)[i] = pb;
}

// ---------------- GEMM1: H = relu(A @ W1^T + b1), A gathered on the fly ----
// A row r = b*128 + m  ->  concat( X[b, idx_M[b,m], :256], molvec[b, :256] )
// block = one (b, n-tile): blockIdx.x = b (row tile of 128), blockIdx.y = n0/128
__global__ __launch_bounds__(256) void gemm1_kernel(
    const float* __restrict__ X, const float* __restrict__ mol,
    const int* __restrict__ idxp, const unsigned short* __restrict__ W1b,
    const float* __restrict__ b1, unsigned short* __restrict__ H) {
    __shared__ __align__(16) unsigned short Asm[128 * 32];
    __shared__ __align__(16) unsigned short Bsm[128 * 32];

    const int t = threadIdx.x;
    const int lane = t & 63, w = t >> 6;
    const int b = blockIdx.x;
    const int n0 = blockIdx.y * 128;
    const int wr = (w >> 1) * 64, wc = (w & 1) * 64;
    const int lr = lane & 15, quad = lane >> 4;

    // A staging role: thread t stages row (t>>1), cols [(t&1)*16, +16)
    const int arow = t >> 1;
    const int acol = (t & 1) * 16;
    const int idx = idxp[b * MM + arow];
    const float* Xrow = X + ((size_t)b * NN + idx) * OUTD;
    const float* mvrow = mol + (size_t)b * MOLD;

    f32x4 acc[4][4];
#pragma unroll
    for (int mi = 0; mi < 4; ++mi)
#pragma unroll
        for (int ni = 0; ni < 4; ++ni) acc[mi][ni] = {0.f, 0.f, 0.f, 0.f};

    for (int ki = 0; ki < 16; ++ki) {
        const int kt = ki * 32;
        // ---- stage A (gather + cast) ----
        const float* src = (kt < OUTD) ? (Xrow + kt + acol) : (mvrow + (kt - OUTD) + acol);
        const float4* s4 = (const float4*)src;
        float4 v0 = s4[0], v1 = s4[1], v2 = s4[2], v3 = s4[3];
        unsigned short* dst = &Asm[arow * 32 + acol];
        ushort4 p;
        p.x = f2bf(v0.x); p.y = f2bf(v0.y); p.z = f2bf(v0.z); p.w = f2bf(v0.w);
        *(ushort4*)(dst + 0) = p;
        p.x = f2bf(v1.x); p.y = f2bf(v1.y); p.z = f2bf(v1.z); p.w = f2bf(v1.w);
        *(ushort4*)(dst + 4) = p;
        p.x = f2bf(v2.x); p.y = f2bf(v2.y); p.z = f2bf(v2.z); p.w = f2bf(v2.w);
        *(ushort4*)(dst + 8) = p;
        p.x = f2bf(v3.x); p.y = f2bf(v3.y); p.z = f2bf(v3.z); p.w = f2bf(v3.w);
        *(ushort4*)(dst + 12) = p;
        // ---- stage B (W1b rows n0..n0+127, k slice) via global_load_lds ----
#pragma unroll
        for (int j = 0; j < 2; ++j) {
            const int cidx = j * 4 + w;             // chunk: 64 lanes x 16B
            const int s = cidx * 64 + lane;         // segment id: row=s>>2, seg=s&3
            const unsigned short* gb = W1b + (size_t)(n0 + (s >> 2)) * K1 + kt + (s & 3) * 8;
            __builtin_amdgcn_global_load_lds((AS_GLOBAL*)gb, (AS_LDS*)(Bsm + cidx * 512), 16, 0, 0);
        }
        __syncthreads();
        // ---- compute: 4x4 MFMA 16x16x32 per wave ----
        s16x8 af[4], bfr[4];
#pragma unroll
        for (int i = 0; i < 4; ++i)
            af[i] = *(const s16x8*)&Asm[(wr + i * 16 + lr) * 32 + quad * 8];
#pragma unroll
        for (int i = 0; i < 4; ++i)
            bfr[i] = *(const s16x8*)&Bsm[(wc + i * 16 + lr) * 32 + quad * 8];
#pragma unroll
        for (int mi = 0; mi < 4; ++mi)
#pragma unroll
            for (int ni = 0; ni < 4; ++ni)
                acc[mi][ni] = __builtin_amdgcn_mfma_f32_16x16x32_bf16(
                    __builtin_bit_cast(bf16x8, af[mi]),
                    __builtin_bit_cast(bf16x8, bfr[ni]), acc[mi][ni], 0, 0, 0);
        __syncthreads();
    }

    // epilogue: +b1, relu, bf16 store to H
    float bias[4];
#pragma unroll
    for (int ni = 0; ni < 4; ++ni) bias[ni] = b1[n0 + wc + ni * 16 + lr];
    const int row0 = b * 128;
#pragma unroll
    for (int mi = 0; mi < 4; ++mi) {
#pragma unroll
        for (int ni = 0; ni < 4; ++ni) {
            const int gcol = n0 + wc + ni * 16 + lr;
#pragma unroll
            for (int rr = 0; rr < 4; ++rr) {
                const int grow = row0 + wr + mi * 16 + quad * 4 + rr;
                float v = acc[mi][ni][rr] + bias[ni];
                v = v > 0.f ? v : 0.f;
                H[(size_t)grow * IND + gcol] = f2bf(v);
            }
        }
    }
}

// ---------------- GEMM2: out = H @ W2^T + b2 (fp32 out) ----------------
__global__ __launch_bounds__(256) void gemm2_kernel(
    const unsigned short* __restrict__ Hb, const unsigned short* __restrict__ W2b,
    const float* __restrict__ b2, float* __restrict__ out) {
    __shared__ __align__(16) unsigned short Asm[128 * 32];
    __shared__ __align__(16) unsigned short Bsm[128 * 32];

    const int t = threadIdx.x;
    const int lane = t & 63, w = t >> 6;
    const int row0 = blockIdx.x * 128;
    const int n0 = blockIdx.y * 128;
    const int wr = (w >> 1) * 64, wc = (w & 1) * 64;
    const int lr = lane & 15, quad = lane >> 4;

    f32x4 acc[4][4];
#pragma unroll
    for (int mi = 0; mi < 4; ++mi)
#pragma unroll
        for (int ni = 0; ni < 4; ++ni) acc[mi][ni] = {0.f, 0.f, 0.f, 0.f};

    for (int ki = 0; ki < 16; ++ki) {
        const int kt = ki * 32;
#pragma unroll
        for (int j = 0; j < 2; ++j) {
            const int cidx = j * 4 + w;
            const int s = cidx * 64 + lane;
            const unsigned short* ga = Hb + (size_t)(row0 + (s >> 2)) * IND + kt + (s & 3) * 8;
            __builtin_amdgcn_global_load_lds((AS_GLOBAL*)ga, (AS_LDS*)(Asm + cidx * 512), 16, 0, 0);
            const unsigned short* gb = W2b + (size_t)(n0 + (s >> 2)) * IND + kt + (s & 3) * 8;
            __builtin_amdgcn_global_load_lds((AS_GLOBAL*)gb, (AS_LDS*)(Bsm + cidx * 512), 16, 0, 0);
        }
        __syncthreads();
        s16x8 af[4], bfr[4];
#pragma unroll
        for (int i = 0; i < 4; ++i)
            af[i] = *(const s16x8*)&Asm[(wr + i * 16 + lr) * 32 + quad * 8];
#pragma unroll
        for (int i = 0; i < 4; ++i)
            bfr[i] = *(const s16x8*)&Bsm[(wc + i * 16 + lr) * 32 + quad * 8];
#pragma unroll
        for (int mi = 0; mi < 4; ++mi)
#pragma unroll
            for (int ni = 0; ni < 4; ++ni)
                acc[mi][ni] = __builtin_amdgcn_mfma_f32_16x16x32_bf16(
                    __builtin_bit_cast(bf16x8, af[mi]),
                    __builtin_bit_cast(bf16x8, bfr[ni]), acc[mi][ni], 0, 0, 0);
        __syncthreads();
    }

    float bias[4];
#pragma unroll
    for (int ni = 0; ni < 4; ++ni) bias[ni] = b2[n0 + wc + ni * 16 + lr];
#pragma unroll
    for (int mi = 0; mi < 4; ++mi) {
#pragma unroll
        for (int ni = 0; ni < 4; ++ni) {
            const int gcol = n0 + wc + ni * 16 + lr;
#pragma unroll
            for (int rr = 0; rr < 4; ++rr) {
                const int grow = row0 + wr + mi * 16 + quad * 4 + rr;
                out[(size_t)grow * IND + gcol] = acc[mi][ni][rr] + bias[ni];
            }
        }
    }
}

extern "C" void kernel_launch(void* const* d_in, const int* in_sizes, int n_in,
                              void* d_out, int out_size, void* d_ws, size_t ws_size,
                              hipStream_t stream) {
    const float* X = (const float*)d_in[0];       // [512,1024,256]
    const float* mol = (const float*)d_in[1];     // [512,256]
    const int* idx = (const int*)d_in[2];         // [512,128]
    const float* W1 = (const float*)d_in[3];      // [512,512]
    const float* b1 = (const float*)d_in[4];      // [512]
    const float* W2 = (const float*)d_in[5];      // [512,512]
    const float* b2 = (const float*)d_in[6];      // [512]
    float* out = (float*)d_out;                   // [65536,512]

    // workspace layout: W1b (512KiB) | W2b (512KiB) | H bf16 (64MiB)
    unsigned short* W1b = (unsigned short*)d_ws;
    unsigned short* W2b = W1b + 512 * 512;
    unsigned short* H = W2b + 512 * 512;

    prep_weights<<<256, 256, 0, stream>>>(W1, W2, W1b, W2b);
    gemm1_kernel<<<dim3(BB, IND / 128), 256, 0, stream>>>(X, mol, idx, W1b, b1, H);
    gemm2_kernel<<<dim3(RROWS / 128, IND / 128), 256, 0, stream>>>(H, W2b, b2, out);
}